// Round 6
// baseline (131.367 us; speedup 1.0000x reference)
//
#include <hip/hip_runtime.h>
#include <stdint.h>

#define BATCH 4
#define NPTS 4096
#define KNN 11            // K+1 neighbors including self
#define LPQ 16            // lanes per query
#define QPB 8             // queries per block (r19: was 16)
#define NTHREADS (QPB * LPQ)      // 128 threads = 2 waves
#define CHUNK 512         // LDS candidate chunk (r19: was 1024)
#define NCHUNK (NPTS / CHUNK)     // 8
#define CPL (CHUNK / LPQ)         // 32 candidates per lane per chunk
#define BUFN 10           // per-lane qualifier buffer slots
#define SENT_BITS 0x433FFFFFFFFFFFFFll

// monotone float -> uint mapping (ascending)
__device__ __forceinline__ unsigned sortable_f32(float d) {
    unsigned b = __float_as_uint(d);
    unsigned m = (unsigned)(((int)b) >> 31) | 0x80000000u;
    return b ^ m;
}

// Fused exact 11-NN + MLP. FROZEN d2 arithmetic (verified r4-r12):
//   sq_j = fl(fl(x2)+fl(y2)) + fl(z2); dot = fma chain; d2 = fl(si+sj)-fl(2t)
//   (computed as fmaf(-2,t,sqq+sqj): bit-identical since 2t is exact;
//    verified passing r15-r18).
// top-k ascending d2, ties -> lower index; key = double with bits
// 0x433<<52 | sortable(d2)<<12 | j  (f64 order == (d2 asc, j asc)).
// r19 = r13 per-thread program VERBATIM (r15/r18 proved the straight-line
// inner loop codegen is load-bearing; r14/r16/r17 proved resource nudges
// trigger allocator pathologies) + ONE packaging change: 128-thread blocks
// (QPB=8, CHUNK=512, LDS 18.6KB -> 8 blocks/CU resident). Same 16-waves/CU
// ceiling, but grid=2048 gives 8 blocks/CU with 2-wave backfill granularity
// -> addresses the measured fill deficit (Occupancy 32% vs 50% structural:
// 1024-block grid = exactly 4/CU, zero backfill; uneven block runtimes
// strand CUs partially idle). Hot loop, flush cadence, tau schedule,
// merges, MLP: untouched.
__global__ __launch_bounds__(NTHREADS, 4) void fused_kernel(
    const float* __restrict__ pos, const float* __restrict__ vel,
    const float* __restrict__ initc,
    const float* __restrict__ W1, const float* __restrict__ b1,
    const float* __restrict__ W2, const float* __restrict__ b2,
    const float* __restrict__ W3, const float* __restrict__ b3,
    float* __restrict__ out)
{
#pragma clang fp contract(off)
    // skewed float4 (x,y,z,sq): idx + (idx>>6) -> partitions offset by 16B
    __shared__ float4 sp[CHUNK + (CHUNK >> 6)];
    // slot-major lane-private buffers: lanes 8B apart -> 2-way -> free
    __shared__ unsigned long long buf[BUFN * NTHREADS];

    int b    = blockIdx.x >> 9;           // 512 blocks per batch
    int qblk = blockIdx.x & 511;
    int tid  = threadIdx.x;
    const float* pb = pos + (size_t)b * NPTS * 3;

    int q = tid >> 4, p = tid & 15;
    int i = qblk * QPB + q;               // query index within batch

    float xq = pb[3*i], yq = pb[3*i+1], zq = pb[3*i+2];
    float sqq = xq*xq + yq*yq + zq*zq;    // contract(off): np sum order

    double kd[KNN];
#pragma unroll
    for (int k = 0; k < KNN; ++k) kd[k] = __longlong_as_double(SENT_BITS);
    float tau_f = __builtin_inff();       // stale-conservative gate threshold
    int cnt = 0, nflush = 0;

    for (int c = 0; c < NCHUNK; ++c) {
        if (c) __syncthreads();
        for (int j = tid; j < CHUNK; j += NTHREADS) {
            int g = c * CHUNK + j;
            float x = pb[3*g], y = pb[3*g+1], z = pb[3*g+2];
            float sq = x*x + y*y + z*z;   // FROZEN staged sq
            sp[j + (j >> 6)] = make_float4(x, y, z, sq);
        }
        __syncthreads();

        // lane p's range j = p*CPL + jl; (j>>6) is constant over the range
        int sbase = p * CPL + ((p * CPL) >> 6);
        int jg    = c * CHUNK + p * CPL;
        for (int jl = 0; jl < CPL; jl += 4) {
            // 4 back-to-back LDS reads + 4 independent d2 chains (ILP)
            float4 c0 = sp[sbase + jl + 0];
            float4 c1 = sp[sbase + jl + 1];
            float4 c2 = sp[sbase + jl + 2];
            float4 c3 = sp[sbase + jl + 3];
            float t0 = xq*c0.x, t1 = xq*c1.x, t2 = xq*c2.x, t3 = xq*c3.x;
            t0 = fmaf(yq, c0.y, t0); t1 = fmaf(yq, c1.y, t1);
            t2 = fmaf(yq, c2.y, t2); t3 = fmaf(yq, c3.y, t3);
            t0 = fmaf(zq, c0.z, t0); t1 = fmaf(zq, c1.z, t1);
            t2 = fmaf(zq, c2.z, t2); t3 = fmaf(zq, c3.z, t3);
            // fl((sqq+cw) - fl(2t)) == fl((sqq+cw) - 2t): 2t exact -> fma ok
            float d0 = fmaf(-2.0f, t0, sqq + c0.w);
            float d1 = fmaf(-2.0f, t1, sqq + c1.w);
            float d2 = fmaf(-2.0f, t2, sqq + c2.w);
            float d3 = fmaf(-2.0f, t3, sqq + c3.w);

            // f32 gate (== u32 gate by monotonicity); pack only on accept
#pragma unroll
            for (int s = 0; s < 4; ++s) {
                float dv = s == 0 ? d0 : s == 1 ? d1 : s == 2 ? d2 : d3;
                if (dv <= tau_f) {
                    unsigned u  = sortable_f32(dv);
                    unsigned lo = (u << 12) | (unsigned)(jg + jl + s);
                    unsigned hi = 0x43300000u | (u >> 20);
                    buf[cnt * NTHREADS + tid] =
                        ((unsigned long long)hi << 32) | (unsigned long long)lo;
                    ++cnt;
                }
            }

            if (__any(cnt > BUFN - 4)) {
                // ---- flush: drain buffers through the f64 network ----
                for (int k = 0; k < BUFN; ++k) {
                    if (!__any(cnt > k)) break;     // early out (late flushes)
                    unsigned long long kb = buf[k * NTHREADS + tid];
                    double key = (k < cnt) ? __longlong_as_double(kb)
                                           : __longlong_as_double(SENT_BITS);
#pragma unroll
                    for (int kk = KNN-1; kk > 0; --kk) {
                        double mn = fmin(kd[kk], key);
                        kd[kk] = fmax(kd[kk-1], mn);
                    }
                    kd[0] = fmin(kd[0], key);
                }
                cnt = 0;
                if (nflush < 3) {         // exact tau only while it matters
                    ++nflush;
                    double tmp[KNN];
#pragma unroll
                    for (int k = 0; k < KNN; ++k) tmp[k] = kd[k];
                    double h = tmp[0];
#pragma unroll
                    for (int r = 0; r < KNN; ++r) {
                        h = tmp[0];
#pragma unroll
                        for (int m = 1; m <= 8; m <<= 1)
                            h = fmin(h, __shfl_xor(h, m, LPQ));
                        bool own = (__double_as_longlong(tmp[0]) ==
                                    __double_as_longlong(h));
#pragma unroll
                        for (int t2 = 0; t2 < KNN-1; ++t2)
                            tmp[t2] = own ? tmp[t2+1] : tmp[t2];
                        tmp[KNN-1] = own ? __longlong_as_double(SENT_BITS)
                                         : tmp[KNN-1];
                    }
                    unsigned tau_u = (unsigned)((unsigned long long)
                                                __double_as_longlong(h) >> 12);
                    // unsortable: real d2 keys have top bit set
                    tau_f = __uint_as_float(tau_u ^ 0x80000000u);
                }
            }
        }
    }

    // final drain
    for (int k = 0; k < BUFN; ++k) {
        if (!__any(cnt > k)) break;
        unsigned long long kb = buf[k * NTHREADS + tid];
        double key = (k < cnt) ? __longlong_as_double(kb)
                               : __longlong_as_double(SENT_BITS);
#pragma unroll
        for (int kk = KNN-1; kk > 0; --kk) {
            double mn = fmin(kd[kk], key);
            kd[kk] = fmax(kd[kk-1], mn);
        }
        kd[0] = fmin(kd[0], key);
    }

    // destructive 16-lane merge (r8 verbatim) -> res[] = original indices
    unsigned res[KNN];
#pragma unroll
    for (int r = 0; r < KNN; ++r) {
        double h = kd[0];
#pragma unroll
        for (int m = 1; m <= 8; m <<= 1)
            h = fmin(h, __shfl_xor(h, m, LPQ));
        long long hb = __double_as_longlong(h);
        res[r] = (unsigned)(hb & 0xFFF);
        bool own = (__double_as_longlong(kd[0]) == hb);
#pragma unroll
        for (int t = 0; t < KNN-1; ++t) kd[t] = own ? kd[t+1] : kd[t];
        kd[KNN-1] = own ? __longlong_as_double(SENT_BITS) : kd[KNN-1];
    }

    // ---------- fused MLP, lane-parallel, BIT-IDENTICAL to r8 ----------
    const float* vb = vel + (size_t)b * NPTS * 3;

    const float* w0 = W1 + (2*p)   * 66;
    const float* w1 = W1 + (2*p+1) * 66;
    float a0 = b1[2*p], a1 = b1[2*p+1];
#pragma unroll
    for (int k = 1; k < KNN; ++k) {       // ff 0..29: relative positions
        const float* pn = pb + 3*(int)res[k];
        float dx = pn[0] - xq, dy = pn[1] - yq, dz = pn[2] - zq;
        int ff = 3*(k-1);
        a0 = fmaf(dx, w0[ff+0], a0); a1 = fmaf(dx, w1[ff+0], a1);
        a0 = fmaf(dy, w0[ff+1], a0); a1 = fmaf(dy, w1[ff+1], a1);
        a0 = fmaf(dz, w0[ff+2], a0); a1 = fmaf(dz, w1[ff+2], a1);
    }
#pragma unroll
    for (int k = 0; k < KNN; ++k) {       // ff 30..62: velocities
        const float* vn = vb + 3*(int)res[k];
        int ff = 30 + 3*k;
        a0 = fmaf(vn[0], w0[ff+0], a0); a1 = fmaf(vn[0], w1[ff+0], a1);
        a0 = fmaf(vn[1], w0[ff+1], a0); a1 = fmaf(vn[1], w1[ff+1], a1);
        a0 = fmaf(vn[2], w0[ff+2], a0); a1 = fmaf(vn[2], w1[ff+2], a1);
    }
    float c0i = initc[b*3+0], c1i = initc[b*3+1], c2i = initc[b*3+2];
    a0 = fmaf(c0i, w0[63], a0); a1 = fmaf(c0i, w1[63], a1);
    a0 = fmaf(c1i, w0[64], a0); a1 = fmaf(c1i, w1[64], a1);
    a0 = fmaf(c2i, w0[65], a0); a1 = fmaf(c2i, w1[65], a1);

    float h2 = b2[p];
    const float* w2 = W2 + p * 32;
#pragma unroll
    for (int ii = 0; ii < 32; ++ii) {
        float h1v = __shfl((ii & 1) ? a1 : a0, ii >> 1, LPQ);
        h2 = fmaf(h1v, w2[ii], h2);
    }
    int o3 = p < 6 ? p : 0;
    float po = b3[o3];
    const float* w3 = W3 + o3 * 16;
#pragma unroll
    for (int ii = 0; ii < 16; ++ii) {
        float h2v = __shfl(h2, ii, LPQ);
        po = fmaf(h2v, w3[ii], po);
    }
    float resid = (p == 0) ? xq : (p == 1) ? yq : (p == 2) ? zq : 0.0f;
    po += resid;                           // residual on first 3 channels

    if (p < 6)
        out[((size_t)b * NPTS + (size_t)i) * 6 + p] = po;
}

extern "C" void kernel_launch(void* const* d_in, const int* in_sizes, int n_in,
                              void* d_out, int out_size, void* d_ws, size_t ws_size,
                              hipStream_t stream) {
    const float* pos   = (const float*)d_in[0];
    const float* vel   = (const float*)d_in[1];
    const float* initc = (const float*)d_in[2];
    const float* W1    = (const float*)d_in[3];
    const float* b1    = (const float*)d_in[4];
    const float* W2    = (const float*)d_in[5];
    const float* b2    = (const float*)d_in[6];
    const float* W3    = (const float*)d_in[7];
    const float* b3    = (const float*)d_in[8];
    float* out = (float*)d_out;

    fused_kernel<<<dim3(BATCH * (NPTS / QPB)), dim3(NTHREADS), 0, stream>>>(
        pos, vel, initc, W1, b1, W2, b2, W3, b3, out);
}

// Round 7
// 125.399 us; speedup vs baseline: 1.0476x; 1.0476x over previous
//
#include <hip/hip_runtime.h>
#include <stdint.h>

#define BATCH 4
#define NPTS 4096
#define KNN 11            // K+1 neighbors including self
#define LPQ 16            // lanes per query
#define QPB 16            // queries per block
#define CHUNK 1024        // LDS candidate chunk
#define NCHUNK (NPTS / CHUNK)     // 4
#define CPL (CHUNK / LPQ)         // 64 candidates per lane per chunk
#define BUFN 10           // per-lane qualifier buffer slots
#define SENT_BITS 0x433FFFFFFFFFFFFFll

// monotone float -> uint mapping (ascending)
__device__ __forceinline__ unsigned sortable_f32(float d) {
    unsigned b = __float_as_uint(d);
    unsigned m = (unsigned)(((int)b) >> 31) | 0x80000000u;
    return b ^ m;
}

// Fused exact 11-NN + MLP. FROZEN d2 arithmetic (verified r4-r12):
//   sq_j = fl(fl(x2)+fl(y2)) + fl(z2); dot = fma chain; d2 = fl(si+sj)-fl(2t).
// top-k ascending d2, ties -> lower index; key = double with bits
// 0x433<<52 | sortable(d2)<<12 | j  (f64 order == (d2 asc, j asc)).
// r20 = round-0 65.5us kernel BYTE-IDENTICAL except the occupancy attribute:
// launch_bounds(256,4) -> launch_bounds(256) + amdgpu_waves_per_eu(4,4).
// Rationale: every (·,4+) config spills ~40B/thread of f64 state to scratch
// (WRITE_SIZE 10.6MB vs 393KB of actual output; r14's (256,2) build used 88
// VGPR with WRITE exactly = output). The allocator chases the 8-waves/EU
// tier (<=64 VGPR) and spills the kd[]/tmp[] f64 arrays -- on the serial
// drain/merge critical path. Pinning waves/EU at exactly 4 gives it the
// full 128-VGPR budget (4x128 = 512 = whole per-EU pool, zero occupancy
// cost) and removes the incentive to spill. No semantic change whatsoever.
__global__ __launch_bounds__(256)
__attribute__((amdgpu_waves_per_eu(4, 4))) void fused_kernel(
    const float* __restrict__ pos, const float* __restrict__ vel,
    const float* __restrict__ initc,
    const float* __restrict__ W1, const float* __restrict__ b1,
    const float* __restrict__ W2, const float* __restrict__ b2,
    const float* __restrict__ W3, const float* __restrict__ b3,
    float* __restrict__ out)
{
#pragma clang fp contract(off)
    // skewed float4 (x,y,z,sq): idx + (idx>>6) -> partitions offset by 16B
    __shared__ float4 sp[CHUNK + LPQ];
    // slot-major lane-private buffers: lanes 8B apart -> 2-way -> free
    __shared__ unsigned long long buf[BUFN * 256];

    int b    = blockIdx.x >> 8;           // 256 blocks per batch
    int qblk = blockIdx.x & 255;
    int tid  = threadIdx.x;
    const float* pb = pos + (size_t)b * NPTS * 3;

    int q = tid >> 4, p = tid & 15;
    int i = qblk * QPB + q;               // query index within batch

    float xq = pb[3*i], yq = pb[3*i+1], zq = pb[3*i+2];
    float sqq = xq*xq + yq*yq + zq*zq;    // contract(off): np sum order

    double kd[KNN];
#pragma unroll
    for (int k = 0; k < KNN; ++k) kd[k] = __longlong_as_double(SENT_BITS);
    float tau_f = __builtin_inff();       // stale-conservative gate threshold
    int cnt = 0, nflush = 0;

    for (int c = 0; c < NCHUNK; ++c) {
        if (c) __syncthreads();
        for (int j = tid; j < CHUNK; j += 256) {
            int g = c * CHUNK + j;
            float x = pb[3*g], y = pb[3*g+1], z = pb[3*g+2];
            float sq = x*x + y*y + z*z;   // FROZEN staged sq
            sp[j + (j >> 6)] = make_float4(x, y, z, sq);
        }
        __syncthreads();

        int sbase = p * (CPL + 1);
        int jg    = c * CHUNK + p * CPL;
        for (int jl = 0; jl < CPL; jl += 4) {
            // 4 back-to-back LDS reads + 4 independent d2 chains (ILP)
            float4 c0 = sp[sbase + jl + 0];
            float4 c1 = sp[sbase + jl + 1];
            float4 c2 = sp[sbase + jl + 2];
            float4 c3 = sp[sbase + jl + 3];
            float t0 = xq*c0.x, t1 = xq*c1.x, t2 = xq*c2.x, t3 = xq*c3.x;
            t0 = fmaf(yq, c0.y, t0); t1 = fmaf(yq, c1.y, t1);
            t2 = fmaf(yq, c2.y, t2); t3 = fmaf(yq, c3.y, t3);
            t0 = fmaf(zq, c0.z, t0); t1 = fmaf(zq, c1.z, t1);
            t2 = fmaf(zq, c2.z, t2); t3 = fmaf(zq, c3.z, t3);
            float d0 = (sqq + c0.w) - 2.0f*t0;
            float d1 = (sqq + c1.w) - 2.0f*t1;
            float d2 = (sqq + c2.w) - 2.0f*t2;
            float d3 = (sqq + c3.w) - 2.0f*t3;

            // f32 gate (== u32 gate by monotonicity); pack only on accept
#pragma unroll
            for (int s = 0; s < 4; ++s) {
                float dv = s == 0 ? d0 : s == 1 ? d1 : s == 2 ? d2 : d3;
                if (dv <= tau_f) {
                    unsigned u  = sortable_f32(dv);
                    unsigned lo = (u << 12) | (unsigned)(jg + jl + s);
                    unsigned hi = 0x43300000u | (u >> 20);
                    buf[cnt * 256 + tid] =
                        ((unsigned long long)hi << 32) | (unsigned long long)lo;
                    ++cnt;
                }
            }

            if (__any(cnt > BUFN - 4)) {
                // ---- flush: drain buffers through the f64 network ----
                for (int k = 0; k < BUFN; ++k) {
                    if (!__any(cnt > k)) break;     // early out (late flushes)
                    unsigned long long kb = buf[k * 256 + tid];
                    double key = (k < cnt) ? __longlong_as_double(kb)
                                           : __longlong_as_double(SENT_BITS);
#pragma unroll
                    for (int kk = KNN-1; kk > 0; --kk) {
                        double mn = fmin(kd[kk], key);
                        kd[kk] = fmax(kd[kk-1], mn);
                    }
                    kd[0] = fmin(kd[0], key);
                }
                cnt = 0;
                if (nflush < 3) {         // exact tau only while it matters
                    ++nflush;
                    double tmp[KNN];
#pragma unroll
                    for (int k = 0; k < KNN; ++k) tmp[k] = kd[k];
                    double h = tmp[0];
#pragma unroll
                    for (int r = 0; r < KNN; ++r) {
                        h = tmp[0];
#pragma unroll
                        for (int m = 1; m <= 8; m <<= 1)
                            h = fmin(h, __shfl_xor(h, m, LPQ));
                        bool own = (__double_as_longlong(tmp[0]) ==
                                    __double_as_longlong(h));
#pragma unroll
                        for (int t2 = 0; t2 < KNN-1; ++t2)
                            tmp[t2] = own ? tmp[t2+1] : tmp[t2];
                        tmp[KNN-1] = own ? __longlong_as_double(SENT_BITS)
                                         : tmp[KNN-1];
                    }
                    unsigned tau_u = (unsigned)((unsigned long long)
                                                __double_as_longlong(h) >> 12);
                    // unsortable: real d2 keys have top bit set
                    tau_f = __uint_as_float(tau_u ^ 0x80000000u);
                }
            }
        }
    }

    // final drain
    for (int k = 0; k < BUFN; ++k) {
        if (!__any(cnt > k)) break;
        unsigned long long kb = buf[k * 256 + tid];
        double key = (k < cnt) ? __longlong_as_double(kb)
                               : __longlong_as_double(SENT_BITS);
#pragma unroll
        for (int kk = KNN-1; kk > 0; --kk) {
            double mn = fmin(kd[kk], key);
            kd[kk] = fmax(kd[kk-1], mn);
        }
        kd[0] = fmin(kd[0], key);
    }

    // destructive 16-lane merge (r8 verbatim) -> res[] = original indices
    unsigned res[KNN];
#pragma unroll
    for (int r = 0; r < KNN; ++r) {
        double h = kd[0];
#pragma unroll
        for (int m = 1; m <= 8; m <<= 1)
            h = fmin(h, __shfl_xor(h, m, LPQ));
        long long hb = __double_as_longlong(h);
        res[r] = (unsigned)(hb & 0xFFF);
        bool own = (__double_as_longlong(kd[0]) == hb);
#pragma unroll
        for (int t = 0; t < KNN-1; ++t) kd[t] = own ? kd[t+1] : kd[t];
        kd[KNN-1] = own ? __longlong_as_double(SENT_BITS) : kd[KNN-1];
    }

    // ---------- fused MLP, lane-parallel, BIT-IDENTICAL to r8 ----------
    const float* vb = vel + (size_t)b * NPTS * 3;

    const float* w0 = W1 + (2*p)   * 66;
    const float* w1 = W1 + (2*p+1) * 66;
    float a0 = b1[2*p], a1 = b1[2*p+1];
#pragma unroll
    for (int k = 1; k < KNN; ++k) {       // ff 0..29: relative positions
        const float* pn = pb + 3*(int)res[k];
        float dx = pn[0] - xq, dy = pn[1] - yq, dz = pn[2] - zq;
        int ff = 3*(k-1);
        a0 = fmaf(dx, w0[ff+0], a0); a1 = fmaf(dx, w1[ff+0], a1);
        a0 = fmaf(dy, w0[ff+1], a0); a1 = fmaf(dy, w1[ff+1], a1);
        a0 = fmaf(dz, w0[ff+2], a0); a1 = fmaf(dz, w1[ff+2], a1);
    }
#pragma unroll
    for (int k = 0; k < KNN; ++k) {       // ff 30..62: velocities
        const float* vn = vb + 3*(int)res[k];
        int ff = 30 + 3*k;
        a0 = fmaf(vn[0], w0[ff+0], a0); a1 = fmaf(vn[0], w1[ff+0], a1);
        a0 = fmaf(vn[1], w0[ff+1], a0); a1 = fmaf(vn[1], w1[ff+1], a1);
        a0 = fmaf(vn[2], w0[ff+2], a0); a1 = fmaf(vn[2], w1[ff+2], a1);
    }
    float c0i = initc[b*3+0], c1i = initc[b*3+1], c2i = initc[b*3+2];
    a0 = fmaf(c0i, w0[63], a0); a1 = fmaf(c0i, w1[63], a1);
    a0 = fmaf(c1i, w0[64], a0); a1 = fmaf(c1i, w1[64], a1);
    a0 = fmaf(c2i, w0[65], a0); a1 = fmaf(c2i, w1[65], a1);

    float h2 = b2[p];
    const float* w2 = W2 + p * 32;
#pragma unroll
    for (int ii = 0; ii < 32; ++ii) {
        float h1v = __shfl((ii & 1) ? a1 : a0, ii >> 1, LPQ);
        h2 = fmaf(h1v, w2[ii], h2);
    }
    int o3 = p < 6 ? p : 0;
    float po = b3[o3];
    const float* w3 = W3 + o3 * 16;
#pragma unroll
    for (int ii = 0; ii < 16; ++ii) {
        float h2v = __shfl(h2, ii, LPQ);
        po = fmaf(h2v, w3[ii], po);
    }
    float resid = (p == 0) ? xq : (p == 1) ? yq : (p == 2) ? zq : 0.0f;
    po += resid;                           // residual on first 3 channels

    if (p < 6)
        out[((size_t)b * NPTS + (size_t)i) * 6 + p] = po;
}

extern "C" void kernel_launch(void* const* d_in, const int* in_sizes, int n_in,
                              void* d_out, int out_size, void* d_ws, size_t ws_size,
                              hipStream_t stream) {
    const float* pos   = (const float*)d_in[0];
    const float* vel   = (const float*)d_in[1];
    const float* initc = (const float*)d_in[2];
    const float* W1    = (const float*)d_in[3];
    const float* b1    = (const float*)d_in[4];
    const float* W2    = (const float*)d_in[5];
    const float* b2    = (const float*)d_in[6];
    const float* W3    = (const float*)d_in[7];
    const float* b3    = (const float*)d_in[8];
    float* out = (float*)d_out;

    fused_kernel<<<dim3(BATCH * (NPTS / QPB)), dim3(256), 0, stream>>>(
        pos, vel, initc, W1, b1, W2, b2, W3, b3, out);
}

// Round 9
// 123.163 us; speedup vs baseline: 1.0666x; 1.0182x over previous
//
#include <hip/hip_runtime.h>
#include <stdint.h>

#define BATCH 4
#define NPTS 4096
#define KNN 11            // K+1 neighbors including self
#define LPQ 16            // lanes per query
#define QPB 16            // queries per block
#define CHUNK 1024        // LDS candidate chunk
#define NCHUNK (NPTS / CHUNK)     // 4
#define CPL (CHUNK / LPQ)         // 64 candidates per lane per chunk
#define BUFN 10           // per-lane qualifier buffer slots
#define SENT_BITS 0x433FFFFFFFFFFFFFll

// monotone float -> uint mapping (ascending)
__device__ __forceinline__ unsigned sortable_f32(float d) {
    unsigned b = __float_as_uint(d);
    unsigned m = (unsigned)(((int)b) >> 31) | 0x80000000u;
    return b ^ m;
}

// Fused exact 11-NN + MLP. FROZEN d2 arithmetic (verified r4-r12):
//   sq_j = fl(fl(x2)+fl(y2)) + fl(z2); dot = fma chain; d2 = fl(si+sj)-fl(2t).
// top-k ascending d2, ties -> lower index; key = double with bits
// 0x433<<52 | sortable(d2)<<12 | j  (f64 order == (d2 asc, j asc)).
// r21 (resubmit; round-8 run died on container acquisition, not the kernel)
// = r20 + prepass-seeded tau, replacing the in-scan tau bootstrap:
//   after staging chunk 0, each lane computes d2 (textually identical
//   arithmetic -> identical bits) for its first 32 candidates, keeping its
//   f32 min; an 11-round f32 pop across the 16-lane group yields the 11th
//   smallest of the 16 lane-mins. Those mins are actual d2 values of 11
//   distinct candidates, all <= tau -> true 11th-smallest d2 <= tau ->
//   gate conservative -> selection exact (tie-pops only loosen tau).
// This deletes: the tau=inf accept-everything pack storm, the first ~3
// full-buffer drains, all 3 in-scan f64 tau pop-merges, and tmp[11]'s
// live range. Scan inner loop / flush drain / final merge / MLP: verbatim.
__global__ __launch_bounds__(256)
__attribute__((amdgpu_waves_per_eu(4, 4))) void fused_kernel(
    const float* __restrict__ pos, const float* __restrict__ vel,
    const float* __restrict__ initc,
    const float* __restrict__ W1, const float* __restrict__ b1,
    const float* __restrict__ W2, const float* __restrict__ b2,
    const float* __restrict__ W3, const float* __restrict__ b3,
    float* __restrict__ out)
{
#pragma clang fp contract(off)
    // skewed float4 (x,y,z,sq): idx + (idx>>6) -> partitions offset by 16B
    __shared__ float4 sp[CHUNK + LPQ];
    // slot-major lane-private buffers: lanes 8B apart -> 2-way -> free
    __shared__ unsigned long long buf[BUFN * 256];

    int b    = blockIdx.x >> 8;           // 256 blocks per batch
    int qblk = blockIdx.x & 255;
    int tid  = threadIdx.x;
    const float* pb = pos + (size_t)b * NPTS * 3;

    int q = tid >> 4, p = tid & 15;
    int i = qblk * QPB + q;               // query index within batch

    float xq = pb[3*i], yq = pb[3*i+1], zq = pb[3*i+2];
    float sqq = xq*xq + yq*yq + zq*zq;    // contract(off): np sum order

    double kd[KNN];
#pragma unroll
    for (int k = 0; k < KNN; ++k) kd[k] = __longlong_as_double(SENT_BITS);
    float tau_f = __builtin_inff();       // conservative gate threshold
    int cnt = 0;

    for (int c = 0; c < NCHUNK; ++c) {
        if (c) __syncthreads();
        for (int j = tid; j < CHUNK; j += 256) {
            int g = c * CHUNK + j;
            float x = pb[3*g], y = pb[3*g+1], z = pb[3*g+2];
            float sq = x*x + y*y + z*z;   // FROZEN staged sq
            sp[j + (j >> 6)] = make_float4(x, y, z, sq);
        }
        __syncthreads();

        int sbase = p * (CPL + 1);
        int jg    = c * CHUNK + p * CPL;

        if (c == 0) {
            // ---- prepass: seed tau from lane-local mins of 32 cands ----
            float mn = __builtin_inff();
            for (int jl = 0; jl < 32; jl += 4) {
                float4 c0 = sp[sbase + jl + 0];
                float4 c1 = sp[sbase + jl + 1];
                float4 c2 = sp[sbase + jl + 2];
                float4 c3 = sp[sbase + jl + 3];
                float t0 = xq*c0.x, t1 = xq*c1.x, t2 = xq*c2.x, t3 = xq*c3.x;
                t0 = fmaf(yq, c0.y, t0); t1 = fmaf(yq, c1.y, t1);
                t2 = fmaf(yq, c2.y, t2); t3 = fmaf(yq, c3.y, t3);
                t0 = fmaf(zq, c0.z, t0); t1 = fmaf(zq, c1.z, t1);
                t2 = fmaf(zq, c2.z, t2); t3 = fmaf(zq, c3.z, t3);
                float d0 = (sqq + c0.w) - 2.0f*t0;
                float d1 = (sqq + c1.w) - 2.0f*t1;
                float d2 = (sqq + c2.w) - 2.0f*t2;
                float d3 = (sqq + c3.w) - 2.0f*t3;
                mn = fminf(mn, fminf(fminf(d0, d1), fminf(d2, d3)));
            }
            // 11-round pop over the 16-lane group -> 11th smallest lane-min
            float mcur = mn, tau = mn;
#pragma unroll
            for (int r = 0; r < KNN; ++r) {
                float h = mcur;
#pragma unroll
                for (int m = 1; m <= 8; m <<= 1)
                    h = fminf(h, __shfl_xor(h, m, LPQ));
                tau = h;
                mcur = (mcur == h) ? __builtin_inff() : mcur;
            }
            tau_f = tau;
        }

        for (int jl = 0; jl < CPL; jl += 4) {
            // 4 back-to-back LDS reads + 4 independent d2 chains (ILP)
            float4 c0 = sp[sbase + jl + 0];
            float4 c1 = sp[sbase + jl + 1];
            float4 c2 = sp[sbase + jl + 2];
            float4 c3 = sp[sbase + jl + 3];
            float t0 = xq*c0.x, t1 = xq*c1.x, t2 = xq*c2.x, t3 = xq*c3.x;
            t0 = fmaf(yq, c0.y, t0); t1 = fmaf(yq, c1.y, t1);
            t2 = fmaf(yq, c2.y, t2); t3 = fmaf(yq, c3.y, t3);
            t0 = fmaf(zq, c0.z, t0); t1 = fmaf(zq, c1.z, t1);
            t2 = fmaf(zq, c2.z, t2); t3 = fmaf(zq, c3.z, t3);
            float d0 = (sqq + c0.w) - 2.0f*t0;
            float d1 = (sqq + c1.w) - 2.0f*t1;
            float d2 = (sqq + c2.w) - 2.0f*t2;
            float d3 = (sqq + c3.w) - 2.0f*t3;

            // f32 gate (== u32 gate by monotonicity); pack only on accept
#pragma unroll
            for (int s = 0; s < 4; ++s) {
                float dv = s == 0 ? d0 : s == 1 ? d1 : s == 2 ? d2 : d3;
                if (dv <= tau_f) {
                    unsigned u  = sortable_f32(dv);
                    unsigned lo = (u << 12) | (unsigned)(jg + jl + s);
                    unsigned hi = 0x43300000u | (u >> 20);
                    buf[cnt * 256 + tid] =
                        ((unsigned long long)hi << 32) | (unsigned long long)lo;
                    ++cnt;
                }
            }

            if (__any(cnt > BUFN - 4)) {
                // ---- flush: drain buffers through the f64 network ----
                for (int k = 0; k < BUFN; ++k) {
                    if (!__any(cnt > k)) break;     // early out
                    unsigned long long kb = buf[k * 256 + tid];
                    double key = (k < cnt) ? __longlong_as_double(kb)
                                           : __longlong_as_double(SENT_BITS);
#pragma unroll
                    for (int kk = KNN-1; kk > 0; --kk) {
                        double mn2 = fmin(kd[kk], key);
                        kd[kk] = fmax(kd[kk-1], mn2);
                    }
                    kd[0] = fmin(kd[0], key);
                }
                cnt = 0;
            }
        }
    }

    // final drain
    for (int k = 0; k < BUFN; ++k) {
        if (!__any(cnt > k)) break;
        unsigned long long kb = buf[k * 256 + tid];
        double key = (k < cnt) ? __longlong_as_double(kb)
                               : __longlong_as_double(SENT_BITS);
#pragma unroll
        for (int kk = KNN-1; kk > 0; --kk) {
            double mn2 = fmin(kd[kk], key);
            kd[kk] = fmax(kd[kk-1], mn2);
        }
        kd[0] = fmin(kd[0], key);
    }

    // destructive 16-lane merge (r8 verbatim) -> res[] = original indices
    unsigned res[KNN];
#pragma unroll
    for (int r = 0; r < KNN; ++r) {
        double h = kd[0];
#pragma unroll
        for (int m = 1; m <= 8; m <<= 1)
            h = fmin(h, __shfl_xor(h, m, LPQ));
        long long hb = __double_as_longlong(h);
        res[r] = (unsigned)(hb & 0xFFF);
        bool own = (__double_as_longlong(kd[0]) == hb);
#pragma unroll
        for (int t = 0; t < KNN-1; ++t) kd[t] = own ? kd[t+1] : kd[t];
        kd[KNN-1] = own ? __longlong_as_double(SENT_BITS) : kd[KNN-1];
    }

    // ---------- fused MLP, lane-parallel, BIT-IDENTICAL to r8 ----------
    const float* vb = vel + (size_t)b * NPTS * 3;

    const float* w0 = W1 + (2*p)   * 66;
    const float* w1 = W1 + (2*p+1) * 66;
    float a0 = b1[2*p], a1 = b1[2*p+1];
#pragma unroll
    for (int k = 1; k < KNN; ++k) {       // ff 0..29: relative positions
        const float* pn = pb + 3*(int)res[k];
        float dx = pn[0] - xq, dy = pn[1] - yq, dz = pn[2] - zq;
        int ff = 3*(k-1);
        a0 = fmaf(dx, w0[ff+0], a0); a1 = fmaf(dx, w1[ff+0], a1);
        a0 = fmaf(dy, w0[ff+1], a0); a1 = fmaf(dy, w1[ff+1], a1);
        a0 = fmaf(dz, w0[ff+2], a0); a1 = fmaf(dz, w1[ff+2], a1);
    }
#pragma unroll
    for (int k = 0; k < KNN; ++k) {       // ff 30..62: velocities
        const float* vn = vb + 3*(int)res[k];
        int ff = 30 + 3*k;
        a0 = fmaf(vn[0], w0[ff+0], a0); a1 = fmaf(vn[0], w1[ff+0], a1);
        a0 = fmaf(vn[1], w0[ff+1], a0); a1 = fmaf(vn[1], w1[ff+1], a1);
        a0 = fmaf(vn[2], w0[ff+2], a0); a1 = fmaf(vn[2], w1[ff+2], a1);
    }
    float c0i = initc[b*3+0], c1i = initc[b*3+1], c2i = initc[b*3+2];
    a0 = fmaf(c0i, w0[63], a0); a1 = fmaf(c0i, w1[63], a1);
    a0 = fmaf(c1i, w0[64], a0); a1 = fmaf(c1i, w1[64], a1);
    a0 = fmaf(c2i, w0[65], a0); a1 = fmaf(c2i, w1[65], a1);

    float h2 = b2[p];
    const float* w2 = W2 + p * 32;
#pragma unroll
    for (int ii = 0; ii < 32; ++ii) {
        float h1v = __shfl((ii & 1) ? a1 : a0, ii >> 1, LPQ);
        h2 = fmaf(h1v, w2[ii], h2);
    }
    int o3 = p < 6 ? p : 0;
    float po = b3[o3];
    const float* w3 = W3 + o3 * 16;
#pragma unroll
    for (int ii = 0; ii < 16; ++ii) {
        float h2v = __shfl(h2, ii, LPQ);
        po = fmaf(h2v, w3[ii], po);
    }
    float resid = (p == 0) ? xq : (p == 1) ? yq : (p == 2) ? zq : 0.0f;
    po += resid;                           // residual on first 3 channels

    if (p < 6)
        out[((size_t)b * NPTS + (size_t)i) * 6 + p] = po;
}

extern "C" void kernel_launch(void* const* d_in, const int* in_sizes, int n_in,
                              void* d_out, int out_size, void* d_ws, size_t ws_size,
                              hipStream_t stream) {
    const float* pos   = (const float*)d_in[0];
    const float* vel   = (const float*)d_in[1];
    const float* initc = (const float*)d_in[2];
    const float* W1    = (const float*)d_in[3];
    const float* b1    = (const float*)d_in[4];
    const float* W2    = (const float*)d_in[5];
    const float* b2    = (const float*)d_in[6];
    const float* W3    = (const float*)d_in[7];
    const float* b3    = (const float*)d_in[8];
    float* out = (float*)d_out;

    fused_kernel<<<dim3(BATCH * (NPTS / QPB)), dim3(256), 0, stream>>>(
        pos, vel, initc, W1, b1, W2, b2, W3, b3, out);
}